// Round 4
// baseline (446.070 us; speedup 1.0000x reference)
//
#include <hip/hip_runtime.h>
#include <stdint.h>

#define SEQ 2048
#define DHK 1024
#define DHV 1024
#define NB 8

typedef __attribute__((ext_vector_type(8))) short bf16x8;
typedef __attribute__((ext_vector_type(4))) float f32x4;

__device__ __forceinline__ unsigned short f2bf(float f) {
    uint32_t u = __builtin_bit_cast(uint32_t, f);
    u += 0x7fffu + ((u >> 16) & 1u);
    return (unsigned short)(u >> 16);
}

__device__ __forceinline__ void gload_lds16(const unsigned short* g, unsigned short* l) {
    __builtin_amdgcn_global_load_lds(
        (const __attribute__((address_space(1))) void*)g,
        (__attribute__((address_space(3))) void*)l,
        16, 0, 0);
}

// ---------------- convert q: fp32 [B,S,D] -> bf16 same layout ----------------
__global__ __launch_bounds__(256) void cvt_q(const float* __restrict__ in,
                                             unsigned short* __restrict__ out) {
    size_t i = ((size_t)blockIdx.x * 256 + threadIdx.x) * 16;
#pragma unroll
    for (int c = 0; c < 4; ++c) {
        float4 v = *(const float4*)(in + i + c * 4);
        ushort4 o;
        o.x = f2bf(v.x); o.y = f2bf(v.y); o.z = f2bf(v.z); o.w = f2bf(v.w);
        *(ushort4*)(out + i + c * 4) = o;
    }
}

// ------------- transpose+convert: fp32 [B,R,C] -> bf16 [B,C,R] --------------
__global__ __launch_bounds__(256) void tr_cvt(const float* __restrict__ in,
                                              unsigned short* __restrict__ out,
                                              int R, int C) {
    __shared__ float tile[64][65];
    int b  = blockIdx.z;
    int c0 = blockIdx.x * 64, r0 = blockIdx.y * 64;
    const float* ib = in + (size_t)b * R * C;
    unsigned short* ob = out + (size_t)b * R * C;
    int tr = threadIdx.x >> 4;
    int tc = (threadIdx.x & 15) * 4;
#pragma unroll
    for (int it = 0; it < 4; ++it) {
        int r = tr + it * 16;
        float4 v = *(const float4*)(ib + (size_t)(r0 + r) * C + c0 + tc);
        tile[r][tc + 0] = v.x; tile[r][tc + 1] = v.y;
        tile[r][tc + 2] = v.z; tile[r][tc + 3] = v.w;
    }
    __syncthreads();
#pragma unroll
    for (int it = 0; it < 4; ++it) {
        int c = tr + it * 16;
        ushort4 o;
        o.x = f2bf(tile[tc + 0][c]);
        o.y = f2bf(tile[tc + 1][c]);
        o.z = f2bf(tile[tc + 2][c]);
        o.w = f2bf(tile[tc + 3][c]);
        *(ushort4*)(ob + (size_t)(c0 + c) * R + r0 + tc) = o;
    }
}

// --- 128x128 bf16 GEMM, BK=32, dbuf (32KB LDS -> 5 blk/CU), XCD swizzle -----
// MODE 0: E = exp(0.1 * Q@Kt^T) bf16, row sums atomically into L. K=1024,N=2048
// MODE 1: out = (E@Vt^T)/L[row] fp32.                            K=2048,N=1024
template <int MODE>
__global__ __launch_bounds__(256) void attn_gemm(const unsigned short* __restrict__ A,
                                                 const unsigned short* __restrict__ Bt,
                                                 void* __restrict__ Cout,
                                                 float* __restrict__ L) {
    constexpr int K  = (MODE == 0) ? DHK : SEQ;
    constexpr int N  = (MODE == 0) ? SEQ : DHV;
    constexpr int GM = SEQ / 128;
    constexpr int PM = (MODE == 0) ? 8 : 4;
    constexpr int PN = (MODE == 0) ? 8 : 4;
    constexpr int NPM = GM / PM;

    // [2 buffers][128 rows][32 ushorts = 4 slots of 8]
    __shared__ unsigned short As[2][128 * 32];
    __shared__ unsigned short Bs[2][128 * 32];

    int lid   = blockIdx.x;
    int batch = lid & 7;
    int t     = lid >> 3;
    int pi    = t / (PM * PN);
    int wio   = t % (PM * PN);
    int bm    = (pi % NPM) * PM + (wio % PM);
    int bn    = (pi / NPM) * PN + (wio / PM);

    const int tid  = threadIdx.x;
    const int wv   = tid >> 6;
    const int lane = tid & 63;
    const int wm   = wv & 1, wn = wv >> 1;
    const int m16  = lane & 15, q = lane >> 4;

    const unsigned short* Ab = A + (size_t)batch * SEQ * K;
    const unsigned short* Bb = Bt + (size_t)batch * N * K;

    // staging: row = 32 ushorts = 4 chunks of 16B; LDS slot s at row r holds
    // global chunk s^(r&3). Per call: 16 rows x 4 slots. 2 calls each for A,B.
    const int lr = lane >> 2;            // row within call 0..15
    const int g  = (lane & 3) ^ (lr & 3);  // global chunk this lane fetches
    size_t gA[2], gB[2];
    int lofs[2];
#pragma unroll
    for (int c = 0; c < 2; ++c) {
        int rloc = wv * 32 + c * 16 + lr;
        gA[c] = (size_t)(bm * 128 + rloc) * K + g * 8;
        gB[c] = (size_t)(bn * 128 + rloc) * K + g * 8;
        lofs[c] = (wv * 32 + c * 16) * 32;
    }

    f32x4 acc[4][4];
#pragma unroll
    for (int i = 0; i < 4; ++i)
#pragma unroll
        for (int j = 0; j < 4; ++j)
#pragma unroll
            for (int e = 0; e < 4; ++e) acc[i][j][e] = 0.0f;

    const int sw = m16 & 3;  // slot-swizzle key for fragment reads

    // prologue: stage k-tile 0 into buffer 0
#pragma unroll
    for (int c = 0; c < 2; ++c) gload_lds16(Ab + gA[c], &As[0][lofs[c]]);
#pragma unroll
    for (int c = 0; c < 2; ++c) gload_lds16(Bb + gB[c], &Bs[0][lofs[c]]);

    int p = 0;
    for (int kk = 0; kk < K; kk += 32) {
        __syncthreads();  // drains buf-p loads
        if (kk + 32 < K) {
            int np = p ^ 1;
#pragma unroll
            for (int c = 0; c < 2; ++c) gload_lds16(Ab + gA[c] + kk + 32, &As[np][lofs[c]]);
#pragma unroll
            for (int c = 0; c < 2; ++c) gload_lds16(Bb + gB[c] + kk + 32, &Bs[np][lofs[c]]);
        }
        bf16x8 af[4], bfv[4];
#pragma unroll
        for (int tt = 0; tt < 4; ++tt) {
            int rl = wm * 64 + tt * 16 + m16;
            af[tt]  = *(const bf16x8*)&As[p][rl * 32 + (q ^ sw) * 8];
            int rb = wn * 64 + tt * 16 + m16;
            bfv[tt] = *(const bf16x8*)&Bs[p][rb * 32 + (q ^ sw) * 8];
        }
#pragma unroll
        for (int mt = 0; mt < 4; ++mt)
#pragma unroll
            for (int nt = 0; nt < 4; ++nt)
                acc[mt][nt] = __builtin_amdgcn_mfma_f32_16x16x32_bf16(
                    af[mt], bfv[nt], acc[mt][nt], 0, 0, 0);
        p ^= 1;
    }

    // C/D layout: col = lane&15, row = (lane>>4)*4 + reg
    const int i0 = bm * 128 + wm * 64;
    const int t0 = bn * 128 + wn * 64;
    if (MODE == 0) {
        unsigned short* E = (unsigned short*)Cout + (size_t)batch * SEQ * N;
        float rs[4][4];
#pragma unroll
        for (int mt = 0; mt < 4; ++mt)
#pragma unroll
            for (int e = 0; e < 4; ++e) rs[mt][e] = 0.0f;
#pragma unroll
        for (int mt = 0; mt < 4; ++mt)
#pragma unroll
            for (int nt = 0; nt < 4; ++nt)
#pragma unroll
                for (int e = 0; e < 4; ++e) {
                    float v = __expf(0.1f * acc[mt][nt][e]);
                    int i = i0 + mt * 16 + q * 4 + e;
                    int tt = t0 + nt * 16 + m16;
                    E[(size_t)i * N + tt] = f2bf(v);
                    rs[mt][e] += v;
                }
#pragma unroll
        for (int mt = 0; mt < 4; ++mt)
#pragma unroll
            for (int e = 0; e < 4; ++e) {
                float v = rs[mt][e];
                v += __shfl_xor(v, 1);
                v += __shfl_xor(v, 2);
                v += __shfl_xor(v, 4);
                v += __shfl_xor(v, 8);
                if (m16 == 0) atomicAdd(&L[batch * SEQ + i0 + mt * 16 + q * 4 + e], v);
            }
    } else {
        float* O = (float*)Cout + (size_t)batch * SEQ * N;
#pragma unroll
        for (int mt = 0; mt < 4; ++mt)
#pragma unroll
            for (int e = 0; e < 4; ++e) {
                int i = i0 + mt * 16 + q * 4 + e;
                float inv = 1.0f / L[batch * SEQ + i];
#pragma unroll
                for (int nt = 0; nt < 4; ++nt) {
                    int tt = t0 + nt * 16 + m16;
                    O[(size_t)i * N + tt] = acc[mt][nt][e] * inv;
                }
            }
    }
}

extern "C" void kernel_launch(void* const* d_in, const int* in_sizes, int n_in,
                              void* d_out, int out_size, void* d_ws, size_t ws_size,
                              hipStream_t stream) {
    (void)in_sizes; (void)n_in; (void)out_size; (void)ws_size;
    const float* q = (const float*)d_in[0];
    const float* k = (const float*)d_in[1];  // [B, D, S]
    const float* v = (const float*)d_in[2];  // [B, S, Dv]

    char* ws = (char*)d_ws;
    unsigned short* Qb = (unsigned short*)(ws);
    unsigned short* Kt = (unsigned short*)(ws + 33554432);   // bf16 [B, S, D]
    unsigned short* Vt = (unsigned short*)(ws + 67108864);   // bf16 [B, Dv, S]
    unsigned short* E  = (unsigned short*)(ws + 100663296);  // bf16 [B, S, S]
    float* L           = (float*)(ws + 167772160);           // fp32 [B, S]

    hipMemsetAsync(L, 0, NB * SEQ * sizeof(float), stream);

    cvt_q<<<dim3((NB * SEQ * DHK) / (256 * 16)), dim3(256), 0, stream>>>(q, Qb);
    tr_cvt<<<dim3(SEQ / 64, DHK / 64, NB), dim3(256), 0, stream>>>(k, Kt, DHK, SEQ);
    tr_cvt<<<dim3(DHV / 64, SEQ / 64, NB), dim3(256), 0, stream>>>(v, Vt, SEQ, DHV);

    attn_gemm<0><<<dim3(NB * 16 * 16), dim3(256), 0, stream>>>(Qb, Kt, (void*)E, L);
    attn_gemm<1><<<dim3(NB * 16 * 8), dim3(256), 0, stream>>>(E, Vt, d_out, L);
}

// Round 5
// 378.586 us; speedup vs baseline: 1.1783x; 1.1783x over previous
//
#include <hip/hip_runtime.h>
#include <stdint.h>

#define SEQ 2048
#define DHK 1024
#define DHV 1024
#define NB 8

typedef __attribute__((ext_vector_type(8))) short bf16x8;
typedef __attribute__((ext_vector_type(4))) float f32x4;

__device__ __forceinline__ unsigned short f2bf(float f) {
    uint32_t u = __builtin_bit_cast(uint32_t, f);
    u += 0x7fffu + ((u >> 16) & 1u);
    return (unsigned short)(u >> 16);
}

__device__ __forceinline__ void gload_lds16(const unsigned short* g, unsigned short* l) {
    __builtin_amdgcn_global_load_lds(
        (const __attribute__((address_space(1))) void*)g,
        (__attribute__((address_space(3))) void*)l,
        16, 0, 0);
}

// ---- fused convert: q cvt + k transpose-cvt + v transpose-cvt, one launch ----
// blocks [0,4096): q elementwise; [4096,8192): k [B,1024,2048]->Kt [B,2048,1024];
// [8192,12288): v [B,2048,1024]->Vt [B,1024,2048]
__global__ __launch_bounds__(256) void fused_cvt(const float* __restrict__ q,
                                                 const float* __restrict__ k,
                                                 const float* __restrict__ v,
                                                 unsigned short* __restrict__ Qb,
                                                 unsigned short* __restrict__ Kt,
                                                 unsigned short* __restrict__ Vt) {
    __shared__ float tile[64][65];
    int bid = blockIdx.x;
    if (bid < 4096) {
        size_t i = ((size_t)bid * 256 + threadIdx.x) * 16;
#pragma unroll
        for (int c = 0; c < 4; ++c) {
            float4 x = *(const float4*)(q + i + c * 4);
            ushort4 o;
            o.x = f2bf(x.x); o.y = f2bf(x.y); o.z = f2bf(x.z); o.w = f2bf(x.w);
            *(ushort4*)(Qb + i + c * 4) = o;
        }
        return;  // q-blocks never reach the barrier (uniform per block)
    }
    const float* in;
    unsigned short* out;
    int R, C, b, x, y;
    if (bid < 8192) {
        int id = bid - 4096;
        b = id >> 9; int rem = id & 511;
        x = rem & 31; y = rem >> 5;           // x over C/64=32, y over R/64=16
        in = k; out = Kt; R = DHK; C = SEQ;
    } else {
        int id = bid - 8192;
        b = id >> 9; int rem = id & 511;
        x = rem & 15; y = rem >> 4;           // x over C/64=16, y over R/64=32
        in = v; out = Vt; R = SEQ; C = DHV;
    }
    int c0 = x * 64, r0 = y * 64;
    const float* ib = in + (size_t)b * R * C;
    unsigned short* ob = out + (size_t)b * R * C;
    int tr = threadIdx.x >> 4;
    int tc = (threadIdx.x & 15) * 4;
#pragma unroll
    for (int it = 0; it < 4; ++it) {
        int r = tr + it * 16;
        float4 w = *(const float4*)(ib + (size_t)(r0 + r) * C + c0 + tc);
        tile[r][tc + 0] = w.x; tile[r][tc + 1] = w.y;
        tile[r][tc + 2] = w.z; tile[r][tc + 3] = w.w;
    }
    __syncthreads();
#pragma unroll
    for (int it = 0; it < 4; ++it) {
        int c = tr + it * 16;
        ushort4 o;
        o.x = f2bf(tile[tc + 0][c]);
        o.y = f2bf(tile[tc + 1][c]);
        o.z = f2bf(tile[tc + 2][c]);
        o.w = f2bf(tile[tc + 3][c]);
        *(ushort4*)(ob + (size_t)(c0 + c) * R + r0 + tc) = o;
    }
}

// ------- 128x128 bf16 GEMM, BK=64, dbuf-pipelined, XCD/batch swizzle --------
// (R3 structure: 128B LDS rows -> conflict-free; 64KB LDS dbuf)
// MODE 0: E = exp(0.1 * Q@Kt^T) bf16.                     K=1024, N=2048
// MODE 1: out = (E@Vt^T)/rowsum(E) fp32; rowsum via ones-MFMA. K=2048, N=1024
template <int MODE>
__global__ __launch_bounds__(256) void attn_gemm(const unsigned short* __restrict__ A,
                                                 const unsigned short* __restrict__ Bt,
                                                 void* __restrict__ Cout) {
    constexpr int K  = (MODE == 0) ? DHK : SEQ;
    constexpr int N  = (MODE == 0) ? SEQ : DHV;
    constexpr int GM = SEQ / 128;
    constexpr int PM = (MODE == 0) ? 8 : 4;
    constexpr int PN = (MODE == 0) ? 8 : 4;
    constexpr int NPM = GM / PM;

    __shared__ unsigned short As[2][128 * 64];
    __shared__ unsigned short Bs[2][128 * 64];

    int lid   = blockIdx.x;
    int batch = lid & 7;
    int t     = lid >> 3;
    int pi    = t / (PM * PN);
    int wio   = t % (PM * PN);
    int bm    = (pi % NPM) * PM + (wio % PM);
    int bn    = (pi / NPM) * PN + (wio / PM);

    const int tid  = threadIdx.x;
    const int wv   = tid >> 6;
    const int lane = tid & 63;
    const int wm   = wv & 1, wn = wv >> 1;
    const int m16  = lane & 15, q = lane >> 4;

    const unsigned short* Ab = A + (size_t)batch * SEQ * K;
    const unsigned short* Bb = Bt + (size_t)batch * N * K;

    // staging: row = 64 ushorts = 8 chunks of 16B; LDS slot s at row r holds
    // global chunk s^(r&7). Per call: 8 rows x 8 slots. 4 calls each for A,B.
    const int lr8 = lane >> 3;
    const int g   = (lane & 7) ^ lr8;
    size_t gA[4], gB[4];
    int lofs[4];
#pragma unroll
    for (int c = 0; c < 4; ++c) {
        int rloc = wv * 32 + c * 8 + lr8;
        gA[c] = (size_t)(bm * 128 + rloc) * K + g * 8;
        gB[c] = (size_t)(bn * 128 + rloc) * K + g * 8;
        lofs[c] = (wv * 32 + c * 8) * 64;
    }

    f32x4 acc[4][4];
#pragma unroll
    for (int i = 0; i < 4; ++i)
#pragma unroll
        for (int j = 0; j < 4; ++j)
#pragma unroll
            for (int e = 0; e < 4; ++e) acc[i][j][e] = 0.0f;

    f32x4 acc1[4];  // MODE 1 only: rowsum(E) accumulator (E @ ones)
#pragma unroll
    for (int i = 0; i < 4; ++i)
#pragma unroll
        for (int e = 0; e < 4; ++e) acc1[i][e] = 0.0f;
    const short one_bf = (short)0x3F80;
    const bf16x8 ones = {one_bf, one_bf, one_bf, one_bf, one_bf, one_bf, one_bf, one_bf};

    const int sw = m16 & 7;

    // prologue: stage k-tile 0 into buffer 0
#pragma unroll
    for (int c = 0; c < 4; ++c) gload_lds16(Ab + gA[c], &As[0][lofs[c]]);
#pragma unroll
    for (int c = 0; c < 4; ++c) gload_lds16(Bb + gB[c], &Bs[0][lofs[c]]);

    int p = 0;
    for (int kk = 0; kk < K; kk += 64) {
        __syncthreads();  // drains buf-p loads
        if (kk + 64 < K) {
            int np = p ^ 1;
#pragma unroll
            for (int c = 0; c < 4; ++c) gload_lds16(Ab + gA[c] + kk + 64, &As[np][lofs[c]]);
#pragma unroll
            for (int c = 0; c < 4; ++c) gload_lds16(Bb + gB[c] + kk + 64, &Bs[np][lofs[c]]);
        }
#pragma unroll
        for (int ss = 0; ss < 2; ++ss) {
            bf16x8 af[4], bfv[4];
#pragma unroll
            for (int tt = 0; tt < 4; ++tt) {
                int rl = wm * 64 + tt * 16 + m16;
                af[tt]  = *(const bf16x8*)&As[p][rl * 64 + ((ss * 4 + q) ^ sw) * 8];
                int rb = wn * 64 + tt * 16 + m16;
                bfv[tt] = *(const bf16x8*)&Bs[p][rb * 64 + ((ss * 4 + q) ^ sw) * 8];
            }
#pragma unroll
            for (int mt = 0; mt < 4; ++mt)
#pragma unroll
                for (int nt = 0; nt < 4; ++nt)
                    acc[mt][nt] = __builtin_amdgcn_mfma_f32_16x16x32_bf16(
                        af[mt], bfv[nt], acc[mt][nt], 0, 0, 0);
            if (MODE == 1) {
#pragma unroll
                for (int mt = 0; mt < 4; ++mt)
                    acc1[mt] = __builtin_amdgcn_mfma_f32_16x16x32_bf16(
                        af[mt], ones, acc1[mt], 0, 0, 0);
            }
        }
        p ^= 1;
    }

    // C/D layout: col = lane&15, row = (lane>>4)*4 + reg
    const int i0 = bm * 128 + wm * 64;
    const int t0 = bn * 128 + wn * 64;
    if (MODE == 0) {
        unsigned short* E = (unsigned short*)Cout + (size_t)batch * SEQ * N;
#pragma unroll
        for (int mt = 0; mt < 4; ++mt)
#pragma unroll
            for (int e = 0; e < 4; ++e) {
                int i = i0 + mt * 16 + q * 4 + e;
#pragma unroll
                for (int nt = 0; nt < 4; ++nt) {
                    int tt = t0 + nt * 16 + m16;
                    E[(size_t)i * N + tt] = f2bf(__expf(0.1f * acc[mt][nt][e]));
                }
            }
    } else {
        float* O = (float*)Cout + (size_t)batch * SEQ * N;
#pragma unroll
        for (int mt = 0; mt < 4; ++mt)
#pragma unroll
            for (int e = 0; e < 4; ++e) {
                int i = i0 + mt * 16 + q * 4 + e;
                float inv = 1.0f / acc1[mt][e];
#pragma unroll
                for (int nt = 0; nt < 4; ++nt) {
                    int tt = t0 + nt * 16 + m16;
                    O[(size_t)i * N + tt] = acc[mt][nt][e] * inv;
                }
            }
    }
}

extern "C" void kernel_launch(void* const* d_in, const int* in_sizes, int n_in,
                              void* d_out, int out_size, void* d_ws, size_t ws_size,
                              hipStream_t stream) {
    (void)in_sizes; (void)n_in; (void)out_size; (void)ws_size;
    const float* q = (const float*)d_in[0];
    const float* k = (const float*)d_in[1];  // [B, D, S]
    const float* v = (const float*)d_in[2];  // [B, S, Dv]

    char* ws = (char*)d_ws;
    unsigned short* Qb = (unsigned short*)(ws);
    unsigned short* Kt = (unsigned short*)(ws + 33554432);   // bf16 [B, S, D]
    unsigned short* Vt = (unsigned short*)(ws + 67108864);   // bf16 [B, Dv, S]
    unsigned short* E  = (unsigned short*)(ws + 100663296);  // bf16 [B, S, S]

    fused_cvt<<<dim3(12288), dim3(256), 0, stream>>>(q, k, v, Qb, Kt, Vt);
    attn_gemm<0><<<dim3(NB * 16 * 16), dim3(256), 0, stream>>>(Qb, Kt, (void*)E);
    attn_gemm<1><<<dim3(NB * 16 * 8), dim3(256), 0, stream>>>(E, Vt, d_out);
}